// Round 4
// baseline (981.238 us; speedup 1.0000x reference)
//
#include <hip/hip_runtime.h>
#include <hip/hip_bf16.h>

#define B_ 32
#define S_ 2048
#define D_ 1024
#define NB_ 1024   // persistent grid: 4 blocks/CU x 256 CUs, co-resident by construction

// ---------------------------------------------------------------------------
// Device-scope grid barrier (sense via generation counter). bar[0]=cnt, bar[1]=gen.
// Safe because the whole grid is co-resident (1024 blocks, <=128 VGPR, 16.6KB LDS).
// atomicAdd on global memory is device-scope on CDNA; __threadfence() gives the
// release/acquire ordering. clock64 escape hatch: if co-residency ever breaks we
// produce a wrong answer, never a hang.
__device__ __forceinline__ void gsync(unsigned* bar) {
    __syncthreads();
    if (threadIdx.x == 0) {
        __threadfence();  // release: publish this block's phase writes
        unsigned g = *(volatile unsigned*)&bar[1];
        unsigned prev = atomicAdd(&bar[0], 1u);
        if (prev == (unsigned)NB_ - 1u) {
            bar[0] = 0u;
            __threadfence();
            atomicAdd(&bar[1], 1u);
        } else {
            long long t0 = clock64();
            while (*(volatile unsigned*)&bar[1] == g) {
                __builtin_amdgcn_s_sleep(8);
                if (clock64() - t0 > 100000000LL) break;  // escape, never hang
            }
        }
        __threadfence();  // acquire: order subsequent reads
    }
    __syncthreads();
}

// ---------------------------------------------------------------------------
// Init: zero barrier state (workspace is re-poisoned between iterations) and
// probe mask dtype (bool may arrive as u8, i32, or f32).
__global__ void k0_init(unsigned* __restrict__ bar,
                        const unsigned int* __restrict__ mprobe,
                        int* __restrict__ flag) {
    int tid = threadIdx.x;
    if (tid < 2) bar[tid] = 0u;
    bool isI = true, isF = true;
    for (int i = tid * 4; i < tid * 4 + 4; ++i) {
        unsigned v = mprobe[i];
        if (v > 1u) isI = false;
        if (v != 0u && v != 0x3F800000u) isF = false;
    }
    unsigned long long bi = __ballot(isI);
    unsigned long long bf = __ballot(isF);
    if (tid == 0) {
        int f = 0;
        if (bi == ~0ull) f = 1;
        else if (bf == ~0ull) f = 2;
        *flag = f;
    }
}

// ---------------------------------------------------------------------------
// The whole pipeline in one persistent kernel, 5 phases, 4 grid syncs.
// P1 colsum -> P2 ys -> P3 v=W.ys -> P4 logits+z partials -> P5 merge.
__global__ __launch_bounds__(256, 4) void fused_all(
    const float* __restrict__ E, const void* __restrict__ maskp,
    const float* __restrict__ w, float* __restrict__ out_zs,
    float* __restrict__ out_f, float* __restrict__ part_sums,
    float* __restrict__ ys, float* __restrict__ v, float* __restrict__ logits,
    float* __restrict__ part_l, float* __restrict__ part_z,
    const int* __restrict__ flagp, unsigned* __restrict__ bar) {
    int beta = blockIdx.x, tid = threadIdx.x, wave = tid >> 6, lane = tid & 63;
    __shared__ __align__(16) float sm[4160];

    // ---- P1: partial column sums. block -> (b, 64-row chunk). E read #1.
    {
        int b = beta >> 5, chunk = beta & 31;
        const float4* base = (const float4*)(E + (size_t)(b * S_ + chunk * 64) * D_);
        float4 a0 = make_float4(0.f, 0.f, 0.f, 0.f), a1 = a0;
#pragma unroll 4
        for (int i = 0; i < 64; i += 2) {
            float4 e0 = base[(size_t)i * (D_ / 4) + tid];
            float4 e1 = base[(size_t)(i + 1) * (D_ / 4) + tid];
            a0.x += e0.x; a0.y += e0.y; a0.z += e0.z; a0.w += e0.w;
            a1.x += e1.x; a1.y += e1.y; a1.z += e1.z; a1.w += e1.w;
        }
        a0.x += a1.x; a0.y += a1.y; a0.z += a1.z; a0.w += a1.w;
        ((float4*)part_sums)[(size_t)(b * 32 + chunk) * (D_ / 4) + tid] = a0;
    }
    gsync(bar);

    // ---- P2: ys = mean over S. 128 active blocks.
    if (beta < 128) {
        int g = beta * 256 + tid;  // [0, B*D)
        int b = g >> 10, d = g & (D_ - 1);
        float s = 0.f;
#pragma unroll 8
        for (int k = 0; k < 32; ++k) s += part_sums[(size_t)(b * 32 + k) * D_ + d];
        ys[g] = s * (1.0f / S_);
    }
    gsync(bar);

    // ---- P3: v[b,d] = w[d,:].ys[b,:]. 256 active blocks, one wave per d,
    // double-buffered ys prefetch over the b-loop.
    if (beta < 256) {
        int d = beta * 4 + wave;
        const float4* wrow = (const float4*)(w + (size_t)d * D_);
        float4 w0 = wrow[lane], w1 = wrow[64 + lane], w2 = wrow[128 + lane],
               w3 = wrow[192 + lane];
        const float4* y0p = (const float4*)(ys);
        float4 n0 = y0p[lane], n1 = y0p[64 + lane], n2 = y0p[128 + lane],
               n3 = y0p[192 + lane];
        for (int b = 0; b < B_; ++b) {
            float4 y0 = n0, y1 = n1, y2 = n2, y3 = n3;
            if (b + 1 < B_) {
                const float4* yn = (const float4*)(ys + (size_t)(b + 1) * D_);
                n0 = yn[lane]; n1 = yn[64 + lane]; n2 = yn[128 + lane]; n3 = yn[192 + lane];
            }
            float p = w0.x * y0.x + w0.y * y0.y + w0.z * y0.z + w0.w * y0.w;
            p += w1.x * y1.x + w1.y * y1.y + w1.z * y1.z + w1.w * y1.w;
            p += w2.x * y2.x + w2.y * y2.y + w2.z * y2.z + w2.w * y2.w;
            p += w3.x * y3.x + w3.y * y3.y + w3.z * y3.z + w3.w * y3.w;
#pragma unroll
            for (int off = 32; off; off >>= 1) p += __shfl_xor(p, off, 64);
            if (lane == 0) v[(size_t)b * D_ + d] = p;
        }
    }
    gsync(bar);

    // ---- P4: logits + exp weights + z partials. E read #2 (L3-adjacent to P1).
    // Block covers the same 64 rows it colsum'd: (b, chunk). Per-block z via LDS.
    int mf = *flagp;
    {
        int b = beta >> 5, chunk = beta & 31;
        const int* mi = (const int*)maskp;
        const unsigned char* mu = (const unsigned char*)maskp;
        const float* mfl = (const float*)maskp;
        const float4* vf = (const float4*)(v + (size_t)b * D_);
        float4 v0 = vf[lane], v1 = vf[64 + lane], v2 = vf[128 + lane], v3 = vf[192 + lane];
        float4 z0 = make_float4(0.f, 0.f, 0.f, 0.f), z1 = z0, z2 = z0, z3 = z0;
        float lacc = 0.f;
#pragma unroll
        for (int t = 0; t < 2; ++t) {
            int s0 = chunk * 64 + t * 32 + wave * 8;  // 8-row strip per wave
            const float4* row0 = (const float4*)(E + (size_t)(b * S_ + s0) * D_);
            float lg8[8];
#pragma unroll
            for (int grp = 0; grp < 4; ++grp) {  // 2 rows per group
                const float4* ra = row0 + (size_t)(grp * 2) * (D_ / 4);
                const float4* rb = row0 + (size_t)(grp * 2 + 1) * (D_ / 4);
                float4 a0 = ra[lane], a1 = ra[64 + lane], a2 = ra[128 + lane], a3 = ra[192 + lane];
                float4 b0 = rb[lane], b1 = rb[64 + lane], b2 = rb[128 + lane], b3 = rb[192 + lane];
                float p0 = a0.x * v0.x + a0.y * v0.y + a0.z * v0.z + a0.w * v0.w;
                p0 += a1.x * v1.x + a1.y * v1.y + a1.z * v1.z + a1.w * v1.w;
                p0 += a2.x * v2.x + a2.y * v2.y + a2.z * v2.z + a2.w * v2.w;
                p0 += a3.x * v3.x + a3.y * v3.y + a3.z * v3.z + a3.w * v3.w;
                float p1 = b0.x * v0.x + b0.y * v0.y + b0.z * v0.z + b0.w * v0.w;
                p1 += b1.x * v1.x + b1.y * v1.y + b1.z * v1.z + b1.w * v1.w;
                p1 += b2.x * v2.x + b2.y * v2.y + b2.z * v2.z + b2.w * v2.w;
                p1 += b3.x * v3.x + b3.y * v3.y + b3.z * v3.z + b3.w * v3.w;
#pragma unroll
                for (int off = 32; off; off >>= 1) {
                    p0 += __shfl_xor(p0, off, 64);
                    p1 += __shfl_xor(p1, off, 64);
                }
                int r0 = b * S_ + s0 + grp * 2, r1 = r0 + 1;
                int m0 = (mf == 1) ? (mi[r0] != 0)
                                   : (mf == 2 ? (mfl[r0] != 0.0f) : (mu[r0] != 0));
                int m1 = (mf == 1) ? (mi[r1] != 0)
                                   : (mf == 2 ? (mfl[r1] != 0.0f) : (mu[r1] != 0));
                lg8[grp * 2] = m0 ? p0 : -1.0e9f;
                lg8[grp * 2 + 1] = m1 ? p1 : -1.0e9f;
                float e0 = m0 ? __expf(p0) : 0.0f;
                float e1 = m1 ? __expf(p1) : 0.0f;
                z0.x += e0 * a0.x + e1 * b0.x; z0.y += e0 * a0.y + e1 * b0.y;
                z0.z += e0 * a0.z + e1 * b0.z; z0.w += e0 * a0.w + e1 * b0.w;
                z1.x += e0 * a1.x + e1 * b1.x; z1.y += e0 * a1.y + e1 * b1.y;
                z1.z += e0 * a1.z + e1 * b1.z; z1.w += e0 * a1.w + e1 * b1.w;
                z2.x += e0 * a2.x + e1 * b2.x; z2.y += e0 * a2.y + e1 * b2.y;
                z2.z += e0 * a2.z + e1 * b2.z; z2.w += e0 * a2.w + e1 * b2.w;
                z3.x += e0 * a3.x + e1 * b3.x; z3.y += e0 * a3.y + e1 * b3.y;
                z3.z += e0 * a3.z + e1 * b3.z; z3.w += e0 * a3.w + e1 * b3.w;
                lacc += e0 + e1;
            }
            if (lane == 0) {
                float4* lp = (float4*)(logits + (size_t)b * S_ + s0);
                lp[0] = make_float4(lg8[0], lg8[1], lg8[2], lg8[3]);
                lp[1] = make_float4(lg8[4], lg8[5], lg8[6], lg8[7]);
            }
        }
        // block-level reduce of z (4 waves -> 1) and lacc via LDS
        *(float4*)&sm[wave * 1024 + 0 * 256 + lane * 4] = z0;
        *(float4*)&sm[wave * 1024 + 1 * 256 + lane * 4] = z1;
        *(float4*)&sm[wave * 1024 + 2 * 256 + lane * 4] = z2;
        *(float4*)&sm[wave * 1024 + 3 * 256 + lane * 4] = z3;
        if (lane == 0) sm[4096 + wave] = lacc;
        __syncthreads();
        float4 s0v = *(float4*)&sm[0 * 1024 + tid * 4];
        float4 s1v = *(float4*)&sm[1 * 1024 + tid * 4];
        float4 s2v = *(float4*)&sm[2 * 1024 + tid * 4];
        float4 s3v = *(float4*)&sm[3 * 1024 + tid * 4];
        s0v.x += s1v.x + s2v.x + s3v.x; s0v.y += s1v.y + s2v.y + s3v.y;
        s0v.z += s1v.z + s2v.z + s3v.z; s0v.w += s1v.w + s2v.w + s3v.w;
        ((float4*)part_z)[(size_t)(b * 32 + chunk) * (D_ / 4) + tid] = s0v;
        if (tid == 0)
            part_l[b * 32 + chunk] = sm[4096] + sm[4097] + sm[4098] + sm[4099];
    }
    gsync(bar);

    // ---- P5: merge -> zs + f. 256 active blocks: b = beta>>3, d-slab/s-strip x.
    if (beta < 256) {
        int b = beta >> 3, x = beta & 7;
        int cg = tid >> 5, d4 = tid & 31;
        float4 acc = make_float4(0.f, 0.f, 0.f, 0.f);
#pragma unroll
        for (int k = 0; k < 4; ++k) {
            int c = cg + k * 8;
            float4 zv = ((const float4*)part_z)[(size_t)(b * 32 + c) * (D_ / 4) + x * 32 + d4];
            acc.x += zv.x; acc.y += zv.y; acc.z += zv.z; acc.w += zv.w;
        }
        *(float4*)&sm[(cg * 32 + d4) * 4] = acc;
        if (tid < 32) sm[4096 + tid] = part_l[b * 32 + tid];
        __syncthreads();
        float lsum = 0.f;
#pragma unroll
        for (int i = 0; i < 32; ++i) lsum += sm[4096 + i];
        float inv = 1.0f / lsum;
        if (tid < 32) {
            float4 t4 = *(float4*)&sm[tid * 4];
#pragma unroll
            for (int j = 1; j < 8; ++j) {
                float4 u = *(float4*)&sm[(j * 32 + tid) * 4];
                t4.x += u.x; t4.y += u.y; t4.z += u.z; t4.w += u.w;
            }
            ((float4*)out_zs)[(size_t)b * (D_ / 4) + x * 32 + tid] =
                make_float4(t4.x * inv, t4.y * inv, t4.z * inv, t4.w * inv);
        }
        if (tid < 64) {
            float4 lv = ((const float4*)logits)[(size_t)b * (S_ / 4) + x * 64 + tid];
            ((float4*)out_f)[(size_t)b * (S_ / 4) + x * 64 + tid] =
                make_float4(__expf(lv.x) * inv, __expf(lv.y) * inv,
                            __expf(lv.z) * inv, __expf(lv.w) * inv);
        }
    }
}

// ---------------------------------------------------------------------------
extern "C" void kernel_launch(void* const* d_in, const int* in_sizes, int n_in,
                              void* d_out, int out_size, void* d_ws, size_t ws_size,
                              hipStream_t stream) {
    const float* E = (const float*)d_in[0];
    const void* maskp = d_in[1];
    const float* w = (const float*)d_in[2];
    float* out = (float*)d_out;  // [B*D] zs, then [B*S] f

    float* ws = (float*)d_ws;
    float* part_sums = ws;                                   // B*32*D = 4 MiB
    float* ys = part_sums + (size_t)B_ * 32 * D_;            // B*D
    float* v = ys + (size_t)B_ * D_;                         // B*D
    float* logits = v + (size_t)B_ * D_;                     // B*S
    float* part_l = logits + (size_t)B_ * S_;                // B*32
    float* part_z = part_l + B_ * 32;                        // B*32*D = 4 MiB
    int* flag = (int*)(part_z + (size_t)B_ * 32 * D_);       // 1
    unsigned* bar = (unsigned*)(flag + 4);                   // cnt, gen

    k0_init<<<1, 64, 0, stream>>>(bar, (const unsigned int*)maskp, flag);

    float* out_f = out + (size_t)B_ * D_;
    hipLaunchKernelGGL(fused_all, dim3(NB_), dim3(256), 0, stream, E, maskp, w,
                       out, out_f, part_sums, ys, v, logits, part_l, part_z,
                       flag, bar);
    (void)ws_size; (void)in_sizes; (void)n_in; (void)out_size;
}

// Round 5
// 643.156 us; speedup vs baseline: 1.5257x; 1.5257x over previous
//
#include <hip/hip_runtime.h>
#include <hip/hip_bf16.h>

#define B_ 32
#define S_ 2048
#define D_ 1024
#define NB_ 512    // persistent grid: >=2 blocks/CU even at 256 VGPRs -> co-resident
#define NCH 16     // chunks per batch: 128 rows each

// ---------------------------------------------------------------------------
// Device-scope grid barrier (sense via generation counter). bar[0]=cnt, bar[1]=gen.
// Co-residency: 512 blocks of 256 thr; even at the 256-VGPR ceiling that's
// 2 blocks/CU x 256 CUs = 512 resident. clock64 escape hatch: worst case a
// wrong answer, never a hang.
__device__ __forceinline__ void gsync(unsigned* bar) {
    __syncthreads();
    if (threadIdx.x == 0) {
        __threadfence();  // release: publish this block's phase writes
        unsigned g = *(volatile unsigned*)&bar[1];
        unsigned prev = atomicAdd(&bar[0], 1u);
        if (prev == (unsigned)NB_ - 1u) {
            bar[0] = 0u;
            __threadfence();
            atomicAdd(&bar[1], 1u);
        } else {
            long long t0 = clock64();
            while (*(volatile unsigned*)&bar[1] == g) {
                __builtin_amdgcn_s_sleep(8);
                if (clock64() - t0 > 100000000LL) break;  // escape, never hang
            }
        }
        __threadfence();  // acquire: order subsequent reads
    }
    __syncthreads();
}

// ---------------------------------------------------------------------------
// Init: zero barrier state and probe mask dtype (bool may arrive u8/i32/f32).
__global__ void k0_init(unsigned* __restrict__ bar,
                        const unsigned int* __restrict__ mprobe,
                        int* __restrict__ flag) {
    int tid = threadIdx.x;
    if (tid < 2) bar[tid] = 0u;
    bool isI = true, isF = true;
    for (int i = tid * 4; i < tid * 4 + 4; ++i) {
        unsigned v = mprobe[i];
        if (v > 1u) isI = false;
        if (v != 0u && v != 0x3F800000u) isF = false;
    }
    unsigned long long bi = __ballot(isI);
    unsigned long long bf = __ballot(isF);
    if (tid == 0) {
        int f = 0;
        if (bi == ~0ull) f = 1;
        else if (bf == ~0ull) f = 2;
        *flag = f;
    }
}

// ---------------------------------------------------------------------------
// Whole pipeline in one persistent kernel, 5 phases, 4 grid syncs.
// NO second launch_bounds arg: let the allocator use ~100 VGPRs, zero spill.
__global__ __launch_bounds__(256) void fused_all(
    const float* __restrict__ E, const void* __restrict__ maskp,
    const float* __restrict__ w, float* __restrict__ out_zs,
    float* __restrict__ out_f, float* __restrict__ part_sums,
    float* __restrict__ ys, float* __restrict__ v, float* __restrict__ logits,
    float* __restrict__ part_l, float* __restrict__ part_z,
    const int* __restrict__ flagp, unsigned* __restrict__ bar) {
    int beta = blockIdx.x, tid = threadIdx.x, wave = tid >> 6, lane = tid & 63;
    __shared__ __align__(16) float sm[4160];

    // ---- P1: partial column sums. block -> (b, 128-row chunk). E read #1.
    {
        int b = beta >> 4, ch = beta & (NCH - 1);
        const float4* base = (const float4*)(E + (size_t)(b * S_ + ch * 128) * D_);
        float4 a0 = make_float4(0.f, 0.f, 0.f, 0.f), a1 = a0;
#pragma unroll 4
        for (int i = 0; i < 128; i += 2) {
            float4 e0 = base[(size_t)i * (D_ / 4) + tid];
            float4 e1 = base[(size_t)(i + 1) * (D_ / 4) + tid];
            a0.x += e0.x; a0.y += e0.y; a0.z += e0.z; a0.w += e0.w;
            a1.x += e1.x; a1.y += e1.y; a1.z += e1.z; a1.w += e1.w;
        }
        a0.x += a1.x; a0.y += a1.y; a0.z += a1.z; a0.w += a1.w;
        ((float4*)part_sums)[(size_t)(b * NCH + ch) * (D_ / 4) + tid] = a0;
    }
    gsync(bar);

    // ---- P2: ys = mean over S. 128 active blocks.
    if (beta < 128) {
        int g = beta * 256 + tid;  // [0, B*D)
        int b = g >> 10, d = g & (D_ - 1);
        float s = 0.f;
#pragma unroll
        for (int k = 0; k < NCH; ++k) s += part_sums[(size_t)(b * NCH + k) * D_ + d];
        ys[g] = s * (1.0f / S_);
    }
    gsync(bar);

    // ---- P3: v[b,d] = w[d,:].ys[b,:]. 256 active blocks, one wave per d.
    if (beta < 256) {
        int d = beta * 4 + wave;
        const float4* wrow = (const float4*)(w + (size_t)d * D_);
        float4 w0 = wrow[lane], w1 = wrow[64 + lane], w2 = wrow[128 + lane],
               w3 = wrow[192 + lane];
        const float4* y0p = (const float4*)(ys);
        float4 n0 = y0p[lane], n1 = y0p[64 + lane], n2 = y0p[128 + lane],
               n3 = y0p[192 + lane];
        for (int b = 0; b < B_; ++b) {
            float4 y0 = n0, y1 = n1, y2 = n2, y3 = n3;
            if (b + 1 < B_) {
                const float4* yn = (const float4*)(ys + (size_t)(b + 1) * D_);
                n0 = yn[lane]; n1 = yn[64 + lane]; n2 = yn[128 + lane]; n3 = yn[192 + lane];
            }
            float p = w0.x * y0.x + w0.y * y0.y + w0.z * y0.z + w0.w * y0.w;
            p += w1.x * y1.x + w1.y * y1.y + w1.z * y1.z + w1.w * y1.w;
            p += w2.x * y2.x + w2.y * y2.y + w2.z * y2.z + w2.w * y2.w;
            p += w3.x * y3.x + w3.y * y3.y + w3.z * y3.z + w3.w * y3.w;
#pragma unroll
            for (int off = 32; off; off >>= 1) p += __shfl_xor(p, off, 64);
            if (lane == 0) v[(size_t)b * D_ + d] = p;
        }
    }
    gsync(bar);

    // ---- P4: logits + exp weights + z partials. E read #2 (L3-resident).
    int mf = *flagp;
    {
        int b = beta >> 4, ch = beta & (NCH - 1);
        const int* mi = (const int*)maskp;
        const unsigned char* mu = (const unsigned char*)maskp;
        const float* mfl = (const float*)maskp;
        const float4* vf = (const float4*)(v + (size_t)b * D_);
        float4 v0 = vf[lane], v1 = vf[64 + lane], v2 = vf[128 + lane], v3 = vf[192 + lane];
        float4 z0 = make_float4(0.f, 0.f, 0.f, 0.f), z1 = z0, z2 = z0, z3 = z0;
        float lacc = 0.f;
        for (int t = 0; t < 4; ++t) {
            int s0 = ch * 128 + t * 32 + wave * 8;  // 8-row strip per wave
            const float4* row0 = (const float4*)(E + (size_t)(b * S_ + s0) * D_);
            float lg8[8];
#pragma unroll
            for (int grp = 0; grp < 4; ++grp) {  // 2 rows per group
                const float4* ra = row0 + (size_t)(grp * 2) * (D_ / 4);
                const float4* rb = row0 + (size_t)(grp * 2 + 1) * (D_ / 4);
                float4 a0 = ra[lane], a1 = ra[64 + lane], a2 = ra[128 + lane], a3 = ra[192 + lane];
                float4 b0 = rb[lane], b1 = rb[64 + lane], b2 = rb[128 + lane], b3 = rb[192 + lane];
                float p0 = a0.x * v0.x + a0.y * v0.y + a0.z * v0.z + a0.w * v0.w;
                p0 += a1.x * v1.x + a1.y * v1.y + a1.z * v1.z + a1.w * v1.w;
                p0 += a2.x * v2.x + a2.y * v2.y + a2.z * v2.z + a2.w * v2.w;
                p0 += a3.x * v3.x + a3.y * v3.y + a3.z * v3.z + a3.w * v3.w;
                float p1 = b0.x * v0.x + b0.y * v0.y + b0.z * v0.z + b0.w * v0.w;
                p1 += b1.x * v1.x + b1.y * v1.y + b1.z * v1.z + b1.w * v1.w;
                p1 += b2.x * v2.x + b2.y * v2.y + b2.z * v2.z + b2.w * v2.w;
                p1 += b3.x * v3.x + b3.y * v3.y + b3.z * v3.z + b3.w * v3.w;
#pragma unroll
                for (int off = 32; off; off >>= 1) {
                    p0 += __shfl_xor(p0, off, 64);
                    p1 += __shfl_xor(p1, off, 64);
                }
                int r0 = b * S_ + s0 + grp * 2, r1 = r0 + 1;
                int m0 = (mf == 1) ? (mi[r0] != 0)
                                   : (mf == 2 ? (mfl[r0] != 0.0f) : (mu[r0] != 0));
                int m1 = (mf == 1) ? (mi[r1] != 0)
                                   : (mf == 2 ? (mfl[r1] != 0.0f) : (mu[r1] != 0));
                lg8[grp * 2] = m0 ? p0 : -1.0e9f;
                lg8[grp * 2 + 1] = m1 ? p1 : -1.0e9f;
                float e0 = m0 ? __expf(p0) : 0.0f;
                float e1 = m1 ? __expf(p1) : 0.0f;
                z0.x += e0 * a0.x + e1 * b0.x; z0.y += e0 * a0.y + e1 * b0.y;
                z0.z += e0 * a0.z + e1 * b0.z; z0.w += e0 * a0.w + e1 * b0.w;
                z1.x += e0 * a1.x + e1 * b1.x; z1.y += e0 * a1.y + e1 * b1.y;
                z1.z += e0 * a1.z + e1 * b1.z; z1.w += e0 * a1.w + e1 * b1.w;
                z2.x += e0 * a2.x + e1 * b2.x; z2.y += e0 * a2.y + e1 * b2.y;
                z2.z += e0 * a2.z + e1 * b2.z; z2.w += e0 * a2.w + e1 * b2.w;
                z3.x += e0 * a3.x + e1 * b3.x; z3.y += e0 * a3.y + e1 * b3.y;
                z3.z += e0 * a3.z + e1 * b3.z; z3.w += e0 * a3.w + e1 * b3.w;
                lacc += e0 + e1;
            }
            if (lane == 0) {
                float4* lp = (float4*)(logits + (size_t)b * S_ + s0);
                lp[0] = make_float4(lg8[0], lg8[1], lg8[2], lg8[3]);
                lp[1] = make_float4(lg8[4], lg8[5], lg8[6], lg8[7]);
            }
        }
        // block-level reduce of z (4 waves -> 1) and lacc via LDS
        *(float4*)&sm[wave * 1024 + 0 * 256 + lane * 4] = z0;
        *(float4*)&sm[wave * 1024 + 1 * 256 + lane * 4] = z1;
        *(float4*)&sm[wave * 1024 + 2 * 256 + lane * 4] = z2;
        *(float4*)&sm[wave * 1024 + 3 * 256 + lane * 4] = z3;
        if (lane == 0) sm[4096 + wave] = lacc;
        __syncthreads();
        float4 s0v = *(float4*)&sm[0 * 1024 + tid * 4];
        float4 s1v = *(float4*)&sm[1 * 1024 + tid * 4];
        float4 s2v = *(float4*)&sm[2 * 1024 + tid * 4];
        float4 s3v = *(float4*)&sm[3 * 1024 + tid * 4];
        s0v.x += s1v.x + s2v.x + s3v.x; s0v.y += s1v.y + s2v.y + s3v.y;
        s0v.z += s1v.z + s2v.z + s3v.z; s0v.w += s1v.w + s2v.w + s3v.w;
        ((float4*)part_z)[(size_t)(b * NCH + ch) * (D_ / 4) + tid] = s0v;
        if (tid == 0)
            part_l[b * NCH + ch] = sm[4096] + sm[4097] + sm[4098] + sm[4099];
    }
    gsync(bar);

    // ---- P5: merge -> zs + f. 256 active blocks: b = beta>>3, slab x = beta&7.
    if (beta < 256) {
        int b = beta >> 3, x = beta & 7;
        int cg = tid >> 5, d4 = tid & 31;
        float4 acc = make_float4(0.f, 0.f, 0.f, 0.f);
#pragma unroll
        for (int k = 0; k < NCH / 8; ++k) {
            int c = cg + k * 8;
            float4 zv = ((const float4*)part_z)[(size_t)(b * NCH + c) * (D_ / 4) + x * 32 + d4];
            acc.x += zv.x; acc.y += zv.y; acc.z += zv.z; acc.w += zv.w;
        }
        *(float4*)&sm[(cg * 32 + d4) * 4] = acc;
        if (tid < NCH) sm[4096 + tid] = part_l[b * NCH + tid];
        __syncthreads();
        float lsum = 0.f;
#pragma unroll
        for (int i = 0; i < NCH; ++i) lsum += sm[4096 + i];
        float inv = 1.0f / lsum;
        if (tid < 32) {
            float4 t4 = *(float4*)&sm[tid * 4];
#pragma unroll
            for (int j = 1; j < 8; ++j) {
                float4 u = *(float4*)&sm[(j * 32 + tid) * 4];
                t4.x += u.x; t4.y += u.y; t4.z += u.z; t4.w += u.w;
            }
            ((float4*)out_zs)[(size_t)b * (D_ / 4) + x * 32 + tid] =
                make_float4(t4.x * inv, t4.y * inv, t4.z * inv, t4.w * inv);
        }
        if (tid < 64) {
            float4 lv = ((const float4*)logits)[(size_t)b * (S_ / 4) + x * 64 + tid];
            ((float4*)out_f)[(size_t)b * (S_ / 4) + x * 64 + tid] =
                make_float4(__expf(lv.x) * inv, __expf(lv.y) * inv,
                            __expf(lv.z) * inv, __expf(lv.w) * inv);
        }
    }
}

// ---------------------------------------------------------------------------
extern "C" void kernel_launch(void* const* d_in, const int* in_sizes, int n_in,
                              void* d_out, int out_size, void* d_ws, size_t ws_size,
                              hipStream_t stream) {
    const float* E = (const float*)d_in[0];
    const void* maskp = d_in[1];
    const float* w = (const float*)d_in[2];
    float* out = (float*)d_out;  // [B*D] zs, then [B*S] f

    float* ws = (float*)d_ws;
    float* part_sums = ws;                                   // B*NCH*D = 2 MiB
    float* ys = part_sums + (size_t)B_ * NCH * D_;           // B*D
    float* v = ys + (size_t)B_ * D_;                         // B*D
    float* logits = v + (size_t)B_ * D_;                     // B*S
    float* part_l = logits + (size_t)B_ * S_;                // B*NCH
    float* part_z = part_l + B_ * NCH;                       // B*NCH*D = 2 MiB
    int* flag = (int*)(part_z + (size_t)B_ * NCH * D_);      // 1
    unsigned* bar = (unsigned*)(flag + 4);                   // cnt, gen

    k0_init<<<1, 64, 0, stream>>>(bar, (const unsigned int*)maskp, flag);

    float* out_f = out + (size_t)B_ * D_;
    hipLaunchKernelGGL(fused_all, dim3(NB_), dim3(256), 0, stream, E, maskp, w,
                       out, out_f, part_sums, ys, v, logits, part_l, part_z,
                       flag, bar);
    (void)ws_size; (void)in_sizes; (void)n_in; (void)out_size;
}

// Round 6
// 502.896 us; speedup vs baseline: 1.9512x; 1.2789x over previous
//
#include <hip/hip_runtime.h>
#include <hip/hip_bf16.h>

#define B_ 32
#define S_ 2048
#define D_ 1024
#define NB_ 512    // 16 blocks per batch x 32 batches; co-resident (>=2 blocks/CU at <=256 VGPR)
#define NCH 16     // chunks per batch: 128 rows each
#define FSTR 32    // flag stride in uints -> 128 B, one cache line per batch flag

// ---------------------------------------------------------------------------
// Per-batch sync primitives. Writers: __syncthreads -> tid0 {release fence,
// atomicAdd}. Readers: tid0 {spin, acquire fence} -> __syncthreads.
// This mirrors the tid0-fence pattern that was empirically correct in R5
// (buffer_wbl2 / buffer_inv act on the whole local L2; block = 1 CU).
// clock64 escape: worst case wrong answer, never a hang.
__device__ __forceinline__ void publish(unsigned* flag) {
    __syncthreads();
    if (threadIdx.x == 0) {
        __threadfence();           // release: push this block's stores
        atomicAdd(flag, 1u);       // device-scope on CDNA
    }
}
__device__ __forceinline__ void wait_for(unsigned* flag, unsigned tgt) {
    if (threadIdx.x == 0) {
        long long t0 = clock64();
        while (*(volatile unsigned*)flag < tgt) {
            __builtin_amdgcn_s_sleep(2);
            if (clock64() - t0 > 200000000LL) break;  // escape, never hang
        }
        __threadfence();           // acquire: invalidate stale lines
    }
    __syncthreads();
}

// ---------------------------------------------------------------------------
// Init: zero the per-batch flags (workspace is poisoned between iterations).
__global__ void k0_init(unsigned* __restrict__ flags) {
    for (int i = threadIdx.x; i < 3 * B_ * FSTR; i += 256) flags[i] = 0u;
}

// ---------------------------------------------------------------------------
// Whole pipeline, one persistent kernel, NO global barriers — per-batch flags.
// Block beta -> (b = beta>>4, ch = beta&15), owns 128 rows of batch b.
// P1 colsum -> [done1(b)] -> P2 v-slice from part_sums -> [done2(b)] ->
// P3 logits+z -> [done3(b), 16th arriver merges batch b].
__global__ __launch_bounds__(256) void fused_all(
    const float* __restrict__ E, const void* __restrict__ maskp,
    const float* __restrict__ w, float* __restrict__ out_zs,
    float* __restrict__ out_f, float* __restrict__ part_sums,
    float* __restrict__ v, float* __restrict__ logits,
    float* __restrict__ part_l, float* __restrict__ part_z,
    unsigned* __restrict__ flags) {
    int beta = blockIdx.x, tid = threadIdx.x, wave = tid >> 6, lane = tid & 63;
    int b = beta >> 4, ch = beta & (NCH - 1);
    unsigned* done1 = flags;
    unsigned* done2 = flags + B_ * FSTR;
    unsigned* done3 = flags + 2 * B_ * FSTR;
    __shared__ __align__(16) float sm[4160];
    __shared__ int sm_last;

    // ---- mask dtype probe (per-block, registers only; u8 / i32 / f32).
    unsigned mpv = ((const unsigned*)maskp)[tid];
    int allI = __syncthreads_and((int)(mpv <= 1u));
    int allF = __syncthreads_and((int)(mpv == 0u || mpv == 0x3F800000u));
    int mf = allI ? 1 : (allF ? 2 : 0);

    // ---- P1: partial column sums over our 128 rows. E read #1.
    {
        const float4* base = (const float4*)(E + (size_t)(b * S_ + ch * 128) * D_);
        float4 a0 = make_float4(0.f, 0.f, 0.f, 0.f), a1 = a0;
#pragma unroll 4
        for (int i = 0; i < 128; i += 2) {
            float4 e0 = base[(size_t)i * (D_ / 4) + tid];
            float4 e1 = base[(size_t)(i + 1) * (D_ / 4) + tid];
            a0.x += e0.x; a0.y += e0.y; a0.z += e0.z; a0.w += e0.w;
            a1.x += e1.x; a1.y += e1.y; a1.z += e1.z; a1.w += e1.w;
        }
        a0.x += a1.x; a0.y += a1.y; a0.z += a1.z; a0.w += a1.w;
        ((float4*)part_sums)[(size_t)(b * NCH + ch) * (D_ / 4) + tid] = a0;
    }
    publish(&done1[b * FSTR]);

    // ---- P2: wait for batch colsums; cs = sum_k part_sums[b,k,:] into LDS,
    // then v-slice d in [ch*64, ch*64+64): v[b,d] = (w[d,:].cs)/S.
    wait_for(&done1[b * FSTR], NCH);
    {
        float4 c = make_float4(0.f, 0.f, 0.f, 0.f);
#pragma unroll
        for (int k = 0; k < NCH; ++k) {
            float4 p = ((const float4*)part_sums)[(size_t)(b * NCH + k) * (D_ / 4) + tid];
            c.x += p.x; c.y += p.y; c.z += p.z; c.w += p.w;
        }
        *(float4*)&sm[tid * 4] = c;
    }
    __syncthreads();
    {
        const float4* sm4 = (const float4*)sm;
        float4 c0 = sm4[lane], c1 = sm4[64 + lane], c2 = sm4[128 + lane],
               c3 = sm4[192 + lane];
        for (int j = 0; j < 16; ++j) {
            int d = ch * 64 + wave * 16 + j;
            const float4* wrow = (const float4*)(w + (size_t)d * D_);
            float4 w0 = wrow[lane], w1 = wrow[64 + lane], w2 = wrow[128 + lane],
                   w3 = wrow[192 + lane];
            float p = w0.x * c0.x + w0.y * c0.y + w0.z * c0.z + w0.w * c0.w;
            p += w1.x * c1.x + w1.y * c1.y + w1.z * c1.z + w1.w * c1.w;
            p += w2.x * c2.x + w2.y * c2.y + w2.z * c2.z + w2.w * c2.w;
            p += w3.x * c3.x + w3.y * c3.y + w3.z * c3.z + w3.w * c3.w;
#pragma unroll
            for (int off = 32; off; off >>= 1) p += __shfl_xor(p, off, 64);
            if (lane == 0) v[(size_t)b * D_ + d] = p * (1.0f / S_);
        }
    }
    publish(&done2[b * FSTR]);

    // ---- P3: wait for full v[b,:]; logits + exp weights + z partial. E read #2.
    wait_for(&done2[b * FSTR], NCH);
    {
        const int* mi = (const int*)maskp;
        const unsigned char* mu = (const unsigned char*)maskp;
        const float* mfl = (const float*)maskp;
        const float4* vf = (const float4*)(v + (size_t)b * D_);
        float4 v0 = vf[lane], v1 = vf[64 + lane], v2 = vf[128 + lane], v3 = vf[192 + lane];
        float4 z0 = make_float4(0.f, 0.f, 0.f, 0.f), z1 = z0, z2 = z0, z3 = z0;
        float lacc = 0.f;
        for (int t = 0; t < 4; ++t) {
            int s0 = ch * 128 + t * 32 + wave * 8;  // 8-row strip per wave
            const float4* row0 = (const float4*)(E + (size_t)(b * S_ + s0) * D_);
            float lg8[8];
#pragma unroll
            for (int grp = 0; grp < 4; ++grp) {  // 2 rows per group
                const float4* ra = row0 + (size_t)(grp * 2) * (D_ / 4);
                const float4* rb = row0 + (size_t)(grp * 2 + 1) * (D_ / 4);
                float4 a0 = ra[lane], a1 = ra[64 + lane], a2 = ra[128 + lane], a3 = ra[192 + lane];
                float4 b0 = rb[lane], b1 = rb[64 + lane], b2 = rb[128 + lane], b3 = rb[192 + lane];
                float p0 = a0.x * v0.x + a0.y * v0.y + a0.z * v0.z + a0.w * v0.w;
                p0 += a1.x * v1.x + a1.y * v1.y + a1.z * v1.z + a1.w * v1.w;
                p0 += a2.x * v2.x + a2.y * v2.y + a2.z * v2.z + a2.w * v2.w;
                p0 += a3.x * v3.x + a3.y * v3.y + a3.z * v3.z + a3.w * v3.w;
                float p1 = b0.x * v0.x + b0.y * v0.y + b0.z * v0.z + b0.w * v0.w;
                p1 += b1.x * v1.x + b1.y * v1.y + b1.z * v1.z + b1.w * v1.w;
                p1 += b2.x * v2.x + b2.y * v2.y + b2.z * v2.z + b2.w * v2.w;
                p1 += b3.x * v3.x + b3.y * v3.y + b3.z * v3.z + b3.w * v3.w;
#pragma unroll
                for (int off = 32; off; off >>= 1) {
                    p0 += __shfl_xor(p0, off, 64);
                    p1 += __shfl_xor(p1, off, 64);
                }
                int r0 = b * S_ + s0 + grp * 2, r1 = r0 + 1;
                int m0 = (mf == 1) ? (mi[r0] != 0)
                                   : (mf == 2 ? (mfl[r0] != 0.0f) : (mu[r0] != 0));
                int m1 = (mf == 1) ? (mi[r1] != 0)
                                   : (mf == 2 ? (mfl[r1] != 0.0f) : (mu[r1] != 0));
                lg8[grp * 2] = m0 ? p0 : -1.0e9f;
                lg8[grp * 2 + 1] = m1 ? p1 : -1.0e9f;
                float e0 = m0 ? __expf(p0) : 0.0f;
                float e1 = m1 ? __expf(p1) : 0.0f;
                z0.x += e0 * a0.x + e1 * b0.x; z0.y += e0 * a0.y + e1 * b0.y;
                z0.z += e0 * a0.z + e1 * b0.z; z0.w += e0 * a0.w + e1 * b0.w;
                z1.x += e0 * a1.x + e1 * b1.x; z1.y += e0 * a1.y + e1 * b1.y;
                z1.z += e0 * a1.z + e1 * b1.z; z1.w += e0 * a1.w + e1 * b1.w;
                z2.x += e0 * a2.x + e1 * b2.x; z2.y += e0 * a2.y + e1 * b2.y;
                z2.z += e0 * a2.z + e1 * b2.z; z2.w += e0 * a2.w + e1 * b2.w;
                z3.x += e0 * a3.x + e1 * b3.x; z3.y += e0 * a3.y + e1 * b3.y;
                z3.z += e0 * a3.z + e1 * b3.z; z3.w += e0 * a3.w + e1 * b3.w;
                lacc += e0 + e1;
            }
            if (lane == 0) {
                float4* lp = (float4*)(logits + (size_t)b * S_ + s0);
                lp[0] = make_float4(lg8[0], lg8[1], lg8[2], lg8[3]);
                lp[1] = make_float4(lg8[4], lg8[5], lg8[6], lg8[7]);
            }
        }
        // block-level reduce of z (4 waves -> 1) + lacc via LDS
        *(float4*)&sm[wave * 1024 + 0 * 256 + lane * 4] = z0;
        *(float4*)&sm[wave * 1024 + 1 * 256 + lane * 4] = z1;
        *(float4*)&sm[wave * 1024 + 2 * 256 + lane * 4] = z2;
        *(float4*)&sm[wave * 1024 + 3 * 256 + lane * 4] = z3;
        if (lane == 0) sm[4096 + wave] = lacc;
        __syncthreads();
        float4 s0v = *(float4*)&sm[0 * 1024 + tid * 4];
        float4 s1v = *(float4*)&sm[1 * 1024 + tid * 4];
        float4 s2v = *(float4*)&sm[2 * 1024 + tid * 4];
        float4 s3v = *(float4*)&sm[3 * 1024 + tid * 4];
        s0v.x += s1v.x + s2v.x + s3v.x; s0v.y += s1v.y + s2v.y + s3v.y;
        s0v.z += s1v.z + s2v.z + s3v.z; s0v.w += s1v.w + s2v.w + s3v.w;
        ((float4*)part_z)[(size_t)(b * NCH + ch) * (D_ / 4) + tid] = s0v;
        if (tid == 0)
            part_l[b * NCH + ch] = sm[4096] + sm[4097] + sm[4098] + sm[4099];
    }

    // ---- P4: arrive; the 16th arriver of batch b merges (threadFenceReduction).
    __syncthreads();
    if (tid == 0) {
        __threadfence();
        unsigned prev = atomicAdd(&done3[b * FSTR], 1u);
        sm_last = (prev == (unsigned)NCH - 1u);
        if (sm_last) __threadfence();  // acquire before reading others' partials
    }
    __syncthreads();
    if (sm_last) {
        float lsum = 0.f;
#pragma unroll
        for (int k = 0; k < NCH; ++k) lsum += part_l[b * NCH + k];
        float inv = 1.0f / lsum;
        float4 acc = make_float4(0.f, 0.f, 0.f, 0.f);
#pragma unroll
        for (int k = 0; k < NCH; ++k) {
            float4 zv = ((const float4*)part_z)[(size_t)(b * NCH + k) * (D_ / 4) + tid];
            acc.x += zv.x; acc.y += zv.y; acc.z += zv.z; acc.w += zv.w;
        }
        ((float4*)out_zs)[(size_t)b * (D_ / 4) + tid] =
            make_float4(acc.x * inv, acc.y * inv, acc.z * inv, acc.w * inv);
        float4 l0 = ((const float4*)logits)[(size_t)b * (S_ / 4) + tid * 2];
        float4 l1 = ((const float4*)logits)[(size_t)b * (S_ / 4) + tid * 2 + 1];
        ((float4*)out_f)[(size_t)b * (S_ / 4) + tid * 2] =
            make_float4(__expf(l0.x) * inv, __expf(l0.y) * inv,
                        __expf(l0.z) * inv, __expf(l0.w) * inv);
        ((float4*)out_f)[(size_t)b * (S_ / 4) + tid * 2 + 1] =
            make_float4(__expf(l1.x) * inv, __expf(l1.y) * inv,
                        __expf(l1.z) * inv, __expf(l1.w) * inv);
    }
}

// ---------------------------------------------------------------------------
extern "C" void kernel_launch(void* const* d_in, const int* in_sizes, int n_in,
                              void* d_out, int out_size, void* d_ws, size_t ws_size,
                              hipStream_t stream) {
    const float* E = (const float*)d_in[0];
    const void* maskp = d_in[1];
    const float* w = (const float*)d_in[2];
    float* out = (float*)d_out;  // [B*D] zs, then [B*S] f

    float* ws = (float*)d_ws;
    float* part_sums = ws;                                   // B*NCH*D = 2 MiB
    float* v = part_sums + (size_t)B_ * NCH * D_;            // B*D
    float* logits = v + (size_t)B_ * D_;                     // B*S
    float* part_l = logits + (size_t)B_ * S_;                // B*NCH
    float* part_z = part_l + B_ * NCH;                       // B*NCH*D = 2 MiB
    unsigned* flags = (unsigned*)(part_z + (size_t)B_ * NCH * D_);  // 3*B*FSTR

    k0_init<<<1, 256, 0, stream>>>(flags);

    float* out_f = out + (size_t)B_ * D_;
    hipLaunchKernelGGL(fused_all, dim3(NB_), dim3(256), 0, stream, E, maskp, w,
                       out, out_f, part_sums, v, logits, part_l, part_z, flags);
    (void)ws_size; (void)in_sizes; (void)n_in; (void)out_size;
}